// Round 1
// baseline (405.184 us; speedup 1.0000x reference)
//
#include <hip/hip_runtime.h>
#include <stdint.h>

#define DIM 256
#define NPOS 4096
#define NB 4
#define GROUPS 32

typedef __attribute__((ext_vector_type(8))) short short8;
typedef __attribute__((ext_vector_type(4))) short short4v;
typedef __attribute__((ext_vector_type(4))) float f32x4;

__device__ __forceinline__ short f2b(float f) {
  unsigned u = __float_as_uint(f);
  unsigned r = (u + 0x7fffu + ((u >> 16) & 1u)) >> 16;
  return (short)r;
}

// ---------------- weight conversion (f32 -> bf16) ----------------
__global__ void k_convert_w(const float* __restrict__ wq, const float* __restrict__ wp,
                            short* __restrict__ wqb, short* __restrict__ wpb) {
  int i = blockIdx.x * 256 + threadIdx.x;
  if (i < 768 * 256) wqb[i] = f2b(wq[i]);
  if (i < 256 * 256) wpb[i] = f2b(wp[i]);
}

// ---------------- GroupNorm stats: one block per (b,g) ----------------
__global__ void k_gn_stats(const float* __restrict__ x, float* __restrict__ stats) {
  int bg = blockIdx.x;  // b*32+g ; channels are contiguous: base = bg*8*NPOS
  const float4* b4 = (const float4*)(x + (size_t)bg * 8 * NPOS);
  float s = 0.f, ss = 0.f;
  for (int i = threadIdx.x; i < 8192; i += 256) {
    float4 v = b4[i];
    s  += v.x + v.y + v.z + v.w;
    ss += v.x * v.x + v.y * v.y + v.z * v.z + v.w * v.w;
  }
  #pragma unroll
  for (int m = 1; m < 64; m <<= 1) { s += __shfl_xor(s, m, 64); ss += __shfl_xor(ss, m, 64); }
  __shared__ float red[8];
  int wid = threadIdx.x >> 6;
  if ((threadIdx.x & 63) == 0) { red[wid * 2] = s; red[wid * 2 + 1] = ss; }
  __syncthreads();
  if (threadIdx.x == 0) {
    float S = red[0] + red[2] + red[4] + red[6];
    float SS = red[1] + red[3] + red[5] + red[7];
    float mean = S / 32768.f;
    float var = SS / 32768.f - mean * mean;
    stats[bg * 2] = mean;
    stats[bg * 2 + 1] = rsqrtf(var + 1e-6f);
  }
}

// ------------- GroupNorm apply + transpose: x(B,C,N) f32 -> h_t(B,N,C) bf16 -------------
__global__ void k_gn_apply(const float* __restrict__ x, const float* __restrict__ stats,
                           const float* __restrict__ gamma, const float* __restrict__ beta,
                           short* __restrict__ ht) {
  int ct = blockIdx.x, nt = blockIdx.y, b = blockIdx.z;
  int c0 = ct * 64, n0 = nt * 64;
  __shared__ short lt[64 * 72];
  int t = threadIdx.x;
  #pragma unroll
  for (int p = 0; p < 4; ++p) {
    int row = (t >> 4) + p * 16;          // channel-local 0..63
    int colb = (t & 15) * 4;              // n-local
    int c = c0 + row;
    float mean = stats[(b * GROUPS + (c >> 3)) * 2];
    float rstd = stats[(b * GROUPS + (c >> 3)) * 2 + 1];
    float ga = gamma[c], be = beta[c];
    float4 v = *(const float4*)(x + ((size_t)(b * DIM + c)) * NPOS + n0 + colb);
    short4v o;
    o.x = f2b((v.x - mean) * rstd * ga + be);
    o.y = f2b((v.y - mean) * rstd * ga + be);
    o.z = f2b((v.z - mean) * rstd * ga + be);
    o.w = f2b((v.w - mean) * rstd * ga + be);
    *(short4v*)&lt[row * 72 + colb] = o;
  }
  __syncthreads();
  #pragma unroll
  for (int p = 0; p < 2; ++p) {
    int nr = (t >> 3) + p * 32;
    int ch = t & 7;
    short8 o;
    #pragma unroll
    for (int j = 0; j < 8; ++j) o[j] = lt[(ch * 8 + j) * 72 + nr];
    *(short8*)(ht + ((size_t)(b * NPOS + n0 + nr)) * DIM + c0 + ch * 8) = o;
  }
}

// ---------------- gemm_bt: C[M,N] = A[M,K] * B[N,K]^T, K=256, 128x128 tile ----------------
// MODE 0: A=h_t (per batch), B=w_qkv_b; out -> q(N,C) k(N,C) v_t(C,N) bf16, +bias
// MODE 1: A=w_proj_b, B=O (per batch); out -> f32 d_out (C,N), +bias +residual x
template <int MODE>
__launch_bounds__(256, 2)
__global__ void k_gemm(const short* __restrict__ A, const short* __restrict__ Bm,
                       const float* __restrict__ bias,
                       short* __restrict__ qb, short* __restrict__ kb, short* __restrict__ vtb,
                       const float* __restrict__ resid, float* __restrict__ outf) {
  const int K = 256;
  int b = blockIdx.z;
  int m0 = blockIdx.x * 128, n0 = blockIdx.y * 128;
  const short* Ap = (MODE == 0) ? A + (size_t)b * NPOS * K : A;
  const short* Bp = (MODE == 0) ? Bm : Bm + (size_t)b * NPOS * K;

  __shared__ short As[128 * 64], Bs[128 * 64];
  int t = threadIdx.x;
  int lane = t & 63, wid = t >> 6;
  int wm = wid >> 1, wn = wid & 1;
  f32x4 acc[4][4] = {};

  for (int kt = 0; kt < 4; ++kt) {
    int k0 = kt * 64;
    short8 av[4], bv[4];
    #pragma unroll
    for (int p = 0; p < 4; ++p) {
      int ci = t + p * 256;
      int row = ci >> 3, ch = ci & 7;
      av[p] = *(const short8*)(Ap + (size_t)(m0 + row) * K + k0 + ch * 8);
      bv[p] = *(const short8*)(Bp + (size_t)(n0 + row) * K + k0 + ch * 8);
    }
    __syncthreads();  // previous iter's LDS reads complete
    #pragma unroll
    for (int p = 0; p < 4; ++p) {
      int ci = t + p * 256;
      int row = ci >> 3, ch = ci & 7;
      int off = (row * 128 + ch * 16) ^ ((row & 7) << 4);
      *(short8*)((char*)As + off) = av[p];
      *(short8*)((char*)Bs + off) = bv[p];
    }
    __syncthreads();
    #pragma unroll
    for (int ks = 0; ks < 2; ++ks) {
      short8 af[4], bf[4];
      int inner = ks * 64 + (lane >> 4) * 16;
      #pragma unroll
      for (int mi = 0; mi < 4; ++mi) {
        int row = wm * 64 + mi * 16 + (lane & 15);
        af[mi] = *(short8*)((char*)As + ((row * 128 + inner) ^ ((row & 7) << 4)));
      }
      #pragma unroll
      for (int ni = 0; ni < 4; ++ni) {
        int row = wn * 64 + ni * 16 + (lane & 15);
        bf[ni] = *(short8*)((char*)Bs + ((row * 128 + inner) ^ ((row & 7) << 4)));
      }
      #pragma unroll
      for (int mi = 0; mi < 4; ++mi)
        #pragma unroll
        for (int ni = 0; ni < 4; ++ni)
          acc[mi][ni] = __builtin_amdgcn_mfma_f32_16x16x32_bf16(af[mi], bf[ni], acc[mi][ni], 0, 0, 0);
    }
  }

  #pragma unroll
  for (int mi = 0; mi < 4; ++mi)
    #pragma unroll
    for (int ni = 0; ni < 4; ++ni) {
      int gcol = n0 + wn * 64 + ni * 16 + (lane & 15);
      #pragma unroll
      for (int r = 0; r < 4; ++r) {
        int grow = m0 + wm * 64 + mi * 16 + (lane >> 4) * 4 + r;
        if (MODE == 0) {
          float v = acc[mi][ni][r] + bias[gcol];
          short h = f2b(v);
          if (gcol < 256)       qb[((size_t)b * NPOS + grow) * DIM + gcol] = h;
          else if (gcol < 512)  kb[((size_t)b * NPOS + grow) * DIM + gcol - 256] = h;
          else                  vtb[((size_t)b * DIM + gcol - 512) * NPOS + grow] = h;
        } else {
          float v = acc[mi][ni][r] + bias[grow];
          size_t idx = ((size_t)b * DIM + grow) * NPOS + gcol;
          outf[idx] = v + resid[idx];
        }
      }
    }
}

// ---------------- flash attention: Q-tile 64 (16/wave), KV-tile 64, D=256 ----------------
__launch_bounds__(256, 2)
__global__ void k_flash(const short* __restrict__ qb, const short* __restrict__ kb,
                        const short* __restrict__ vtb, short* __restrict__ ob) {
  int b = blockIdx.y;
  int q0 = blockIdx.x * 64;
  int t = threadIdx.x, lane = t & 63, wid = t >> 6;
  __shared__ short Ks[64 * 256];   // [kv][c] swizzled
  __shared__ short Vs[256 * 64];   // [c][kv] swizzled
  __shared__ short Ps[4][16 * 64]; // per-wave [q][kv] swizzled

  // Q fragments (A-frag: row = lane&15, k-chunk = (lane>>4)*8)
  short8 qf[8];
  int qrow = q0 + wid * 16 + (lane & 15);
  const short* qbase = qb + ((size_t)b * NPOS + qrow) * DIM + (lane >> 4) * 8;
  #pragma unroll
  for (int s = 0; s < 8; ++s) qf[s] = *(const short8*)(qbase + s * 32);

  f32x4 oacc[16] = {};
  float rowmax[4] = {-1e30f, -1e30f, -1e30f, -1e30f};
  float rowsum[4] = {0.f, 0.f, 0.f, 0.f};

  const short* kbB = kb + (size_t)b * NPOS * DIM;
  const short* vbB = vtb + (size_t)b * DIM * NPOS;
  const float sscale = 0.0625f;  // 1/sqrt(256)

  for (int kt = 0; kt < NPOS / 64; ++kt) {
    int kv0 = kt * 64;
    short8 kst[8], vst[8];
    #pragma unroll
    for (int p = 0; p < 8; ++p) {
      int ci = t + p * 256;
      int krow = ci >> 5, kch = ci & 31;
      kst[p] = *(const short8*)(kbB + (size_t)(kv0 + krow) * DIM + kch * 8);
      int vrow = ci >> 3, vch = ci & 7;
      vst[p] = *(const short8*)(vbB + (size_t)vrow * NPOS + kv0 + vch * 8);
    }
    __syncthreads();  // everyone done reading previous K/V tiles
    #pragma unroll
    for (int p = 0; p < 8; ++p) {
      int ci = t + p * 256;
      int krow = ci >> 5, kch = ci & 31;
      *(short8*)((char*)Ks + ((krow * 512 + kch * 16) ^ ((krow & 7) << 4))) = kst[p];
      int vrow = ci >> 3, vch = ci & 7;
      *(short8*)((char*)Vs + ((vrow * 128 + vch * 16) ^ ((vrow & 7) << 4))) = vst[p];
    }
    __syncthreads();

    // S = Q K^T   (rows q = (lane>>4)*4+r, cols kv = tt*16 + (lane&15))
    f32x4 sacc[4] = {};
    #pragma unroll
    for (int s = 0; s < 8; ++s) {
      int inner = s * 64 + (lane >> 4) * 16;
      #pragma unroll
      for (int tt = 0; tt < 4; ++tt) {
        int row = tt * 16 + (lane & 15);
        short8 kf = *(short8*)((char*)Ks + ((row * 512 + inner) ^ ((row & 7) << 4)));
        sacc[tt] = __builtin_amdgcn_mfma_f32_16x16x32_bf16(qf[s], kf, sacc[tt], 0, 0, 0);
      }
    }

    // online softmax (wave-parallel: reduce across the 16-lane col group)
    float p4[4][4];
    #pragma unroll
    for (int r = 0; r < 4; ++r) {
      float mx = fmaxf(fmaxf(sacc[0][r], sacc[1][r]), fmaxf(sacc[2][r], sacc[3][r]));
      #pragma unroll
      for (int m = 1; m < 16; m <<= 1) mx = fmaxf(mx, __shfl_xor(mx, m, 64));
      mx *= sscale;
      float mnew = fmaxf(rowmax[r], mx);
      float alpha = __expf(rowmax[r] - mnew);
      rowmax[r] = mnew;
      float ts = 0.f;
      #pragma unroll
      for (int tt = 0; tt < 4; ++tt) {
        float p = __expf(sacc[tt][r] * sscale - mnew);
        p4[tt][r] = p;
        ts += p;
      }
      #pragma unroll
      for (int m = 1; m < 16; m <<= 1) ts += __shfl_xor(ts, m, 64);
      rowsum[r] = rowsum[r] * alpha + ts;
      #pragma unroll
      for (int nt = 0; nt < 16; ++nt) oacc[nt][r] *= alpha;
    }

    // P -> wave-private LDS (bf16, swizzled)
    char* pbase = (char*)Ps[wid];
    #pragma unroll
    for (int r = 0; r < 4; ++r) {
      int row = (lane >> 4) * 4 + r;
      #pragma unroll
      for (int tt = 0; tt < 4; ++tt) {
        int col = tt * 16 + (lane & 15);
        *(short*)(pbase + ((row * 128 + col * 2) ^ ((row & 7) << 4))) = f2b(p4[tt][r]);
      }
    }

    // O += P V   (A-frag from Ps, B-frag from Vs)
    #pragma unroll
    for (int ks = 0; ks < 2; ++ks) {
      int inner = ks * 64 + (lane >> 4) * 16;
      int prow = lane & 15;
      short8 pa = *(short8*)(pbase + ((prow * 128 + inner) ^ ((prow & 7) << 4)));
      #pragma unroll
      for (int nt = 0; nt < 16; ++nt) {
        int row = nt * 16 + (lane & 15);
        short8 vf = *(short8*)((char*)Vs + ((row * 128 + inner) ^ ((row & 7) << 4)));
        oacc[nt] = __builtin_amdgcn_mfma_f32_16x16x32_bf16(pa, vf, oacc[nt], 0, 0, 0);
      }
    }
  }

  // epilogue: O /= l, write bf16 (B,N,C)
  #pragma unroll
  for (int r = 0; r < 4; ++r) {
    float inv = 1.f / rowsum[r];
    int orow = q0 + wid * 16 + (lane >> 4) * 4 + r;
    #pragma unroll
    for (int nt = 0; nt < 16; ++nt) {
      int col = nt * 16 + (lane & 15);
      ob[((size_t)b * NPOS + orow) * DIM + col] = f2b(oacc[nt][r] * inv);
    }
  }
}

extern "C" void kernel_launch(void* const* d_in, const int* in_sizes, int n_in,
                              void* d_out, int out_size, void* d_ws, size_t ws_size,
                              hipStream_t stream) {
  const float* x     = (const float*)d_in[0];
  const float* gamma = (const float*)d_in[1];
  const float* beta  = (const float*)d_in[2];
  const float* wqkv  = (const float*)d_in[3];
  const float* bqkv  = (const float*)d_in[4];
  const float* wproj = (const float*)d_in[5];
  const float* bproj = (const float*)d_in[6];
  float* out = (float*)d_out;

  char* ws = (char*)d_ws;
  float* stats = (float*)ws;
  short* wqb = (short*)(ws + 1024);
  short* wpb = (short*)(ws + 1024 + 393216);
  size_t off = 1024 + 393216 + 131072;
  const size_t SZ = (size_t)NB * NPOS * DIM * sizeof(short);  // 8 MB
  short* ht   = (short*)(ws + off); off += SZ;
  short* qbuf = (short*)(ws + off); off += SZ;
  short* kbuf = (short*)(ws + off); off += SZ;
  short* vtb  = (short*)(ws + off); off += SZ;
  short* obuf = ht;  // h_t dead after QKV gemm; reuse for attention output

  k_convert_w<<<768, 256, 0, stream>>>(wqkv, wproj, wqb, wpb);
  k_gn_stats<<<128, 256, 0, stream>>>(x, stats);
  k_gn_apply<<<dim3(4, 64, NB), 256, 0, stream>>>(x, stats, gamma, beta, ht);
  k_gemm<0><<<dim3(32, 6, NB), 256, 0, stream>>>(ht, wqb, bqkv, qbuf, kbuf, vtb, nullptr, nullptr);
  k_flash<<<dim3(64, NB), 256, 0, stream>>>(qbuf, kbuf, vtb, obuf);
  k_gemm<1><<<dim3(2, 32, NB), 256, 0, stream>>>(wpb, obuf, bproj, nullptr, nullptr, nullptr, x, out);
}

// Round 2
// 222.129 us; speedup vs baseline: 1.8241x; 1.8241x over previous
//
#include <hip/hip_runtime.h>
#include <stdint.h>

#define DIM 256
#define NPOS 4096
#define NB 4
#define GROUPS 32

typedef __attribute__((ext_vector_type(8))) short short8;
typedef __attribute__((ext_vector_type(4))) short short4v;
typedef __attribute__((ext_vector_type(4))) float f32x4;

__device__ __forceinline__ short f2b(float f) {
  unsigned u = __float_as_uint(f);
  unsigned r = (u + 0x7fffu + ((u >> 16) & 1u)) >> 16;
  return (short)r;
}

// ---------------- weight conversion (f32 -> bf16) ----------------
__global__ void k_convert_w(const float* __restrict__ wq, const float* __restrict__ wp,
                            short* __restrict__ wqb, short* __restrict__ wpb) {
  int i = blockIdx.x * 256 + threadIdx.x;
  if (i < 768 * 256) wqb[i] = f2b(wq[i]);
  if (i < 256 * 256) wpb[i] = f2b(wp[i]);
}

// ---------------- GroupNorm stats: one block per (b,g) ----------------
__global__ void k_gn_stats(const float* __restrict__ x, float* __restrict__ stats) {
  int bg = blockIdx.x;
  const float4* b4 = (const float4*)(x + (size_t)bg * 8 * NPOS);
  float s = 0.f, ss = 0.f;
  for (int i = threadIdx.x; i < 8192; i += 256) {
    float4 v = b4[i];
    s  += v.x + v.y + v.z + v.w;
    ss += v.x * v.x + v.y * v.y + v.z * v.z + v.w * v.w;
  }
  #pragma unroll
  for (int m = 1; m < 64; m <<= 1) { s += __shfl_xor(s, m, 64); ss += __shfl_xor(ss, m, 64); }
  __shared__ float red[8];
  int wid = threadIdx.x >> 6;
  if ((threadIdx.x & 63) == 0) { red[wid * 2] = s; red[wid * 2 + 1] = ss; }
  __syncthreads();
  if (threadIdx.x == 0) {
    float S = red[0] + red[2] + red[4] + red[6];
    float SS = red[1] + red[3] + red[5] + red[7];
    float mean = S / 32768.f;
    float var = SS / 32768.f - mean * mean;
    stats[bg * 2] = mean;
    stats[bg * 2 + 1] = rsqrtf(var + 1e-6f);
  }
}

// ------------- GroupNorm apply + transpose: x(B,C,N) f32 -> h_t(B,N,C) bf16 -------------
__global__ void k_gn_apply(const float* __restrict__ x, const float* __restrict__ stats,
                           const float* __restrict__ gamma, const float* __restrict__ beta,
                           short* __restrict__ ht) {
  int ct = blockIdx.x, nt = blockIdx.y, b = blockIdx.z;
  int c0 = ct * 64, n0 = nt * 64;
  __shared__ short lt[64 * 72];
  int t = threadIdx.x;
  #pragma unroll
  for (int p = 0; p < 4; ++p) {
    int row = (t >> 4) + p * 16;
    int colb = (t & 15) * 4;
    int c = c0 + row;
    float mean = stats[(b * GROUPS + (c >> 3)) * 2];
    float rstd = stats[(b * GROUPS + (c >> 3)) * 2 + 1];
    float ga = gamma[c], be = beta[c];
    float4 v = *(const float4*)(x + ((size_t)(b * DIM + c)) * NPOS + n0 + colb);
    short4v o;
    o.x = f2b((v.x - mean) * rstd * ga + be);
    o.y = f2b((v.y - mean) * rstd * ga + be);
    o.z = f2b((v.z - mean) * rstd * ga + be);
    o.w = f2b((v.w - mean) * rstd * ga + be);
    *(short4v*)&lt[row * 72 + colb] = o;
  }
  __syncthreads();
  #pragma unroll
  for (int p = 0; p < 2; ++p) {
    int nr = (t >> 3) + p * 32;
    int ch = t & 7;
    short8 o;
    #pragma unroll
    for (int j = 0; j < 8; ++j) o[j] = lt[(ch * 8 + j) * 72 + nr];
    *(short8*)(ht + ((size_t)(b * NPOS + n0 + nr)) * DIM + c0 + ch * 8) = o;
  }
}

// ---------------- gemm_bt: C[M,N] = A[M,K] * B[N,K]^T, K=256, 128x128 tile ----------------
template <int MODE>
__launch_bounds__(256, 2)
__global__ void k_gemm(const short* __restrict__ A, const short* __restrict__ Bm,
                       const float* __restrict__ bias,
                       short* __restrict__ qb, short* __restrict__ kb, short* __restrict__ vtb,
                       const float* __restrict__ resid, float* __restrict__ outf) {
  const int K = 256;
  int b = blockIdx.z;
  int m0 = blockIdx.x * 128, n0 = blockIdx.y * 128;
  const short* Ap = (MODE == 0) ? A + (size_t)b * NPOS * K : A;
  const short* Bp = (MODE == 0) ? Bm : Bm + (size_t)b * NPOS * K;

  __shared__ short As[128 * 64], Bs[128 * 64];
  int t = threadIdx.x;
  int lane = t & 63, wid = t >> 6;
  int wm = wid >> 1, wn = wid & 1;
  f32x4 acc[4][4] = {};

  for (int kt = 0; kt < 4; ++kt) {
    int k0 = kt * 64;
    short8 av[4], bv[4];
    #pragma unroll
    for (int p = 0; p < 4; ++p) {
      int ci = t + p * 256;
      int row = ci >> 3, ch = ci & 7;
      av[p] = *(const short8*)(Ap + (size_t)(m0 + row) * K + k0 + ch * 8);
      bv[p] = *(const short8*)(Bp + (size_t)(n0 + row) * K + k0 + ch * 8);
    }
    __syncthreads();
    #pragma unroll
    for (int p = 0; p < 4; ++p) {
      int ci = t + p * 256;
      int row = ci >> 3, ch = ci & 7;
      int off = (row * 128 + ch * 16) ^ ((row & 7) << 4);
      *(short8*)((char*)As + off) = av[p];
      *(short8*)((char*)Bs + off) = bv[p];
    }
    __syncthreads();
    #pragma unroll
    for (int ks = 0; ks < 2; ++ks) {
      short8 af[4], bf[4];
      int inner = ks * 64 + (lane >> 4) * 16;
      #pragma unroll
      for (int mi = 0; mi < 4; ++mi) {
        int row = wm * 64 + mi * 16 + (lane & 15);
        af[mi] = *(short8*)((char*)As + ((row * 128 + inner) ^ ((row & 7) << 4)));
      }
      #pragma unroll
      for (int ni = 0; ni < 4; ++ni) {
        int row = wn * 64 + ni * 16 + (lane & 15);
        bf[ni] = *(short8*)((char*)Bs + ((row * 128 + inner) ^ ((row & 7) << 4)));
      }
      #pragma unroll
      for (int mi = 0; mi < 4; ++mi)
        #pragma unroll
        for (int ni = 0; ni < 4; ++ni)
          acc[mi][ni] = __builtin_amdgcn_mfma_f32_16x16x32_bf16(af[mi], bf[ni], acc[mi][ni], 0, 0, 0);
    }
  }

  #pragma unroll
  for (int mi = 0; mi < 4; ++mi)
    #pragma unroll
    for (int ni = 0; ni < 4; ++ni) {
      int gcol = n0 + wn * 64 + ni * 16 + (lane & 15);
      #pragma unroll
      for (int r = 0; r < 4; ++r) {
        int grow = m0 + wm * 64 + mi * 16 + (lane >> 4) * 4 + r;
        if (MODE == 0) {
          float v = acc[mi][ni][r] + bias[gcol];
          short h = f2b(v);
          if (gcol < 256)       qb[((size_t)b * NPOS + grow) * DIM + gcol] = h;
          else if (gcol < 512)  kb[((size_t)b * NPOS + grow) * DIM + gcol - 256] = h;
          else                  vtb[((size_t)b * DIM + gcol - 512) * NPOS + grow] = h;
        } else {
          float v = acc[mi][ni][r] + bias[grow];
          size_t idx = ((size_t)b * DIM + grow) * NPOS + gcol;
          outf[idx] = v + resid[idx];
        }
      }
    }
}

// ---- flash attention: 8 waves = 4 Q-subtiles(16 rows) x 2 KV-halves(2048), KV-tile 32 ----
// LDS map (113 KB):
//   Ks[2]   : [0,32K)    per half 32x256 bf16, row stride 512B, swz ^((row&7)<<4)
//   Vs[2]   : [32K,96K)  per half 256x32 bf16, row stride 128B (padded), swz
//   Ps[8]   : [96K,112K) per wave 16x32 bf16, row stride 128B (padded), swz
//   lm      : [112K,113K) [8 waves][16 rows][2] f32
//   scratch : aliases [0,64K) after main loop: [4 qsub][16][256] f32
__launch_bounds__(512, 1)
__global__ void k_flash(const short* __restrict__ qb, const short* __restrict__ kb,
                        const short* __restrict__ vtb, short* __restrict__ ob) {
  __shared__ __align__(16) char smem[115712];
  short* Ks = (short*)smem;
  char*  Vsb = smem + 32768;
  char*  Psb = smem + 98304;
  float* lm = (float*)(smem + 114688);
  float* scratch = (float*)smem;

  int b = blockIdx.y;
  int q0 = blockIdx.x * 64;
  int t = threadIdx.x, lane = t & 63, wid = t >> 6;
  int qs = wid & 3, sh = wid >> 2;

  const short* kbB = kb + (size_t)b * NPOS * DIM;
  const short* vbB = vtb + (size_t)b * DIM * NPOS;
  const float sscale = 0.0625f;

  // Q fragments
  short8 qf[8];
  int qrow = q0 + qs * 16 + (lane & 15);
  const short* qbase = qb + ((size_t)b * NPOS + qrow) * DIM + (lane >> 4) * 8;
  #pragma unroll
  for (int s = 0; s < 8; ++s) qf[s] = *(const short8*)(qbase + s * 32);

  f32x4 oacc[16] = {};
  float rowmax[4] = {-1e30f, -1e30f, -1e30f, -1e30f};
  float rowsum[4] = {0.f, 0.f, 0.f, 0.f};

  const int NIT = 2048 / 32;  // 64 iters per half
  short8 kst[4], vst[4];

  // prologue: load tile 0 into regs
  {
    #pragma unroll
    for (int p = 0; p < 4; ++p) {
      int ci = t + p * 512;
      int h = ci >> 10, rem = ci & 1023;
      int krow = rem >> 5, kch = rem & 31;
      kst[p] = *(const short8*)(kbB + (size_t)(h * 2048 + krow) * DIM + kch * 8);
      int vrow = rem >> 2, vch = rem & 3;
      vst[p] = *(const short8*)(vbB + (size_t)vrow * NPOS + h * 2048 + vch * 8);
    }
  }

  for (int it = 0; it < NIT; ++it) {
    __syncthreads();  // previous iter's LDS reads done
    #pragma unroll
    for (int p = 0; p < 4; ++p) {
      int ci = t + p * 512;
      int h = ci >> 10, rem = ci & 1023;
      int krow = rem >> 5, kch = rem & 31;
      *(short8*)((char*)Ks + h * 16384 + ((krow * 512 + kch * 16) ^ ((krow & 7) << 4))) = kst[p];
      int vrow = rem >> 2, vch = rem & 3;
      *(short8*)(Vsb + h * 32768 + ((vrow * 128 + vch * 16) ^ ((vrow & 7) << 4))) = vst[p];
    }
    __syncthreads();

    // prefetch next tile (issues early; latency hides under compute below)
    if (it + 1 < NIT) {
      int kv0 = (it + 1) * 32;
      #pragma unroll
      for (int p = 0; p < 4; ++p) {
        int ci = t + p * 512;
        int h = ci >> 10, rem = ci & 1023;
        int krow = rem >> 5, kch = rem & 31;
        kst[p] = *(const short8*)(kbB + (size_t)(h * 2048 + kv0 + krow) * DIM + kch * 8);
        int vrow = rem >> 2, vch = rem & 3;
        vst[p] = *(const short8*)(vbB + (size_t)vrow * NPOS + h * 2048 + kv0 + vch * 8);
      }
    }

    // S = Q K^T (16 rows x 32 kv)
    char* ksh = (char*)Ks + sh * 16384;
    f32x4 sacc[2] = {};
    #pragma unroll
    for (int s = 0; s < 8; ++s) {
      int inner = s * 64 + (lane >> 4) * 16;
      #pragma unroll
      for (int tt = 0; tt < 2; ++tt) {
        int row = tt * 16 + (lane & 15);
        short8 kf = *(short8*)(ksh + ((row * 512 + inner) ^ ((row & 7) << 4)));
        sacc[tt] = __builtin_amdgcn_mfma_f32_16x16x32_bf16(qf[s], kf, sacc[tt], 0, 0, 0);
      }
    }

    // online softmax with defer-max (threshold 8)
    float p4[2][4];
    #pragma unroll
    for (int r = 0; r < 4; ++r) {
      float mx = fmaxf(sacc[0][r], sacc[1][r]);
      #pragma unroll
      for (int m = 1; m < 16; m <<= 1) mx = fmaxf(mx, __shfl_xor(mx, m, 64));
      mx *= sscale;
      if (mx > rowmax[r] + 8.f) {
        float al = __expf(rowmax[r] - mx);
        rowmax[r] = mx;
        rowsum[r] *= al;
        #pragma unroll
        for (int nt = 0; nt < 16; ++nt) oacc[nt][r] *= al;
      }
      float ts = 0.f;
      #pragma unroll
      for (int tt = 0; tt < 2; ++tt) {
        float p = __expf(sacc[tt][r] * sscale - rowmax[r]);
        p4[tt][r] = p;
        ts += p;
      }
      #pragma unroll
      for (int m = 1; m < 16; m <<= 1) ts += __shfl_xor(ts, m, 64);
      rowsum[r] += ts;
    }

    // P -> wave-private LDS (bf16, padded stride 128B, swizzled)
    char* pbase = Psb + wid * 2048;
    #pragma unroll
    for (int r = 0; r < 4; ++r) {
      int row = (lane >> 4) * 4 + r;
      #pragma unroll
      for (int tt = 0; tt < 2; ++tt) {
        int col = tt * 16 + (lane & 15);
        *(short*)(pbase + ((row * 128 + col * 2) ^ ((row & 7) << 4))) = f2b(p4[tt][r]);
      }
    }

    // O += P V
    {
      char* vsh = Vsb + sh * 32768;
      int prow = lane & 15;
      int inner = (lane >> 4) * 16;
      short8 pa = *(short8*)(pbase + ((prow * 128 + inner) ^ ((prow & 7) << 4)));
      #pragma unroll
      for (int nt = 0; nt < 16; ++nt) {
        int row = nt * 16 + (lane & 15);
        short8 vf = *(short8*)(vsh + ((row * 128 + inner) ^ ((row & 7) << 4)));
        oacc[nt] = __builtin_amdgcn_mfma_f32_16x16x32_bf16(pa, vf, oacc[nt], 0, 0, 0);
      }
    }
  }

  // ---- combine the two KV-halves ----
  if ((lane & 15) == 0) {
    #pragma unroll
    for (int r = 0; r < 4; ++r) {
      int row = (lane >> 4) * 4 + r;
      lm[(wid * 16 + row) * 2]     = rowmax[r];
      lm[(wid * 16 + row) * 2 + 1] = rowsum[r];
    }
  }
  __syncthreads();
  float alpha[4], Lfull[4];
  #pragma unroll
  for (int r = 0; r < 4; ++r) {
    int row = (lane >> 4) * 4 + r;
    int pw = wid ^ 4;
    float mo = lm[(pw * 16 + row) * 2];
    float lo = lm[(pw * 16 + row) * 2 + 1];
    float M = fmaxf(rowmax[r], mo);
    alpha[r] = __expf(rowmax[r] - M);
    Lfull[r] = rowsum[r] * alpha[r] + lo * __expf(mo - M);
  }
  if (sh == 0) {
    float* sc = scratch + qs * 4096;
    #pragma unroll
    for (int r = 0; r < 4; ++r) {
      int row = (lane >> 4) * 4 + r;
      #pragma unroll
      for (int nt = 0; nt < 16; ++nt)
        sc[row * 256 + nt * 16 + (lane & 15)] = oacc[nt][r] * alpha[r];
    }
  }
  __syncthreads();
  if (sh == 1) {
    float* sc = scratch + qs * 4096;
    #pragma unroll
    for (int r = 0; r < 4; ++r) {
      int row = (lane >> 4) * 4 + r;
      float inv = 1.f / Lfull[r];
      int orow = q0 + qs * 16 + row;
      #pragma unroll
      for (int nt = 0; nt < 16; ++nt) {
        int col = nt * 16 + (lane & 15);
        float v = (sc[row * 256 + col] + oacc[nt][r] * alpha[r]) * inv;
        ob[((size_t)b * NPOS + orow) * DIM + col] = f2b(v);
      }
    }
  }
}

extern "C" void kernel_launch(void* const* d_in, const int* in_sizes, int n_in,
                              void* d_out, int out_size, void* d_ws, size_t ws_size,
                              hipStream_t stream) {
  const float* x     = (const float*)d_in[0];
  const float* gamma = (const float*)d_in[1];
  const float* beta  = (const float*)d_in[2];
  const float* wqkv  = (const float*)d_in[3];
  const float* bqkv  = (const float*)d_in[4];
  const float* wproj = (const float*)d_in[5];
  const float* bproj = (const float*)d_in[6];
  float* out = (float*)d_out;

  char* ws = (char*)d_ws;
  float* stats = (float*)ws;
  short* wqb = (short*)(ws + 1024);
  short* wpb = (short*)(ws + 1024 + 393216);
  size_t off = 1024 + 393216 + 131072;
  const size_t SZ = (size_t)NB * NPOS * DIM * sizeof(short);  // 8 MB
  short* ht   = (short*)(ws + off); off += SZ;
  short* qbuf = (short*)(ws + off); off += SZ;
  short* kbuf = (short*)(ws + off); off += SZ;
  short* vtb  = (short*)(ws + off); off += SZ;
  short* obuf = ht;  // h_t dead after QKV gemm; reuse for attention output

  k_convert_w<<<768, 256, 0, stream>>>(wqkv, wproj, wqb, wpb);
  k_gn_stats<<<128, 256, 0, stream>>>(x, stats);
  k_gn_apply<<<dim3(4, 64, NB), 256, 0, stream>>>(x, stats, gamma, beta, ht);
  k_gemm<0><<<dim3(32, 6, NB), 256, 0, stream>>>(ht, wqb, bqkv, qbuf, kbuf, vtb, nullptr, nullptr);
  k_flash<<<dim3(64, NB), 512, 0, stream>>>(qbuf, kbuf, vtb, obuf);
  k_gemm<1><<<dim3(2, 32, NB), 256, 0, stream>>>(wpb, obuf, bproj, nullptr, nullptr, nullptr, x, out);
}

// Round 4
// 217.577 us; speedup vs baseline: 1.8623x; 1.0209x over previous
//
#include <hip/hip_runtime.h>
#include <stdint.h>

#define DIM 256
#define NPOS 4096
#define NB 4
#define GROUPS 32

typedef __attribute__((ext_vector_type(8))) short short8;
typedef __attribute__((ext_vector_type(4))) short short4v;
typedef __attribute__((ext_vector_type(4))) float f32x4;
typedef __attribute__((ext_vector_type(2))) unsigned int u32x2;

__device__ __forceinline__ short f2b(float f) {
  unsigned u = __float_as_uint(f);
  unsigned r = (u + 0x7fffu + ((u >> 16) & 1u)) >> 16;
  return (short)r;
}

// ---------------- weight conversion (f32 -> bf16) ----------------
__global__ void k_convert_w(const float* __restrict__ wq, const float* __restrict__ wp,
                            short* __restrict__ wqb, short* __restrict__ wpb) {
  int i = blockIdx.x * 256 + threadIdx.x;
  if (i < 768 * 256) wqb[i] = f2b(wq[i]);
  if (i < 256 * 256) wpb[i] = f2b(wp[i]);
}

// ---------------- GroupNorm stats: one block per (b,g) ----------------
__global__ void k_gn_stats(const float* __restrict__ x, float* __restrict__ stats) {
  int bg = blockIdx.x;
  const float4* b4 = (const float4*)(x + (size_t)bg * 8 * NPOS);
  float s = 0.f, ss = 0.f;
  for (int i = threadIdx.x; i < 8192; i += 256) {
    float4 v = b4[i];
    s  += v.x + v.y + v.z + v.w;
    ss += v.x * v.x + v.y * v.y + v.z * v.z + v.w * v.w;
  }
  #pragma unroll
  for (int m = 1; m < 64; m <<= 1) { s += __shfl_xor(s, m, 64); ss += __shfl_xor(ss, m, 64); }
  __shared__ float red[8];
  int wid = threadIdx.x >> 6;
  if ((threadIdx.x & 63) == 0) { red[wid * 2] = s; red[wid * 2 + 1] = ss; }
  __syncthreads();
  if (threadIdx.x == 0) {
    float S = red[0] + red[2] + red[4] + red[6];
    float SS = red[1] + red[3] + red[5] + red[7];
    float mean = S / 32768.f;
    float var = SS / 32768.f - mean * mean;
    stats[bg * 2] = mean;
    stats[bg * 2 + 1] = rsqrtf(var + 1e-6f);
  }
}

// ------------- GroupNorm apply + transpose: x(B,C,N) f32 -> h_t(B,N,C) bf16 -------------
__global__ void k_gn_apply(const float* __restrict__ x, const float* __restrict__ stats,
                           const float* __restrict__ gamma, const float* __restrict__ beta,
                           short* __restrict__ ht) {
  int ct = blockIdx.x, nt = blockIdx.y, b = blockIdx.z;
  int c0 = ct * 64, n0 = nt * 64;
  __shared__ short lt[64 * 72];
  int t = threadIdx.x;
  #pragma unroll
  for (int p = 0; p < 4; ++p) {
    int row = (t >> 4) + p * 16;
    int colb = (t & 15) * 4;
    int c = c0 + row;
    float mean = stats[(b * GROUPS + (c >> 3)) * 2];
    float rstd = stats[(b * GROUPS + (c >> 3)) * 2 + 1];
    float ga = gamma[c], be = beta[c];
    float4 v = *(const float4*)(x + ((size_t)(b * DIM + c)) * NPOS + n0 + colb);
    short4v o;
    o.x = f2b((v.x - mean) * rstd * ga + be);
    o.y = f2b((v.y - mean) * rstd * ga + be);
    o.z = f2b((v.z - mean) * rstd * ga + be);
    o.w = f2b((v.w - mean) * rstd * ga + be);
    *(short4v*)&lt[row * 72 + colb] = o;
  }
  __syncthreads();
  #pragma unroll
  for (int p = 0; p < 2; ++p) {
    int nr = (t >> 3) + p * 32;
    int ch = t & 7;
    short8 o;
    #pragma unroll
    for (int j = 0; j < 8; ++j) o[j] = lt[(ch * 8 + j) * 72 + nr];
    *(short8*)(ht + ((size_t)(b * NPOS + n0 + nr)) * DIM + c0 + ch * 8) = o;
  }
}

// ---------------- gemm_bt: C[M,N] = A[M,K] * B[N,K]^T, K=256, 128x128 tile ----------------
template <int MODE>
__launch_bounds__(256, 2)
__global__ void k_gemm(const short* __restrict__ A, const short* __restrict__ Bm,
                       const float* __restrict__ bias,
                       short* __restrict__ qb, short* __restrict__ kb, short* __restrict__ vtb,
                       const float* __restrict__ resid, float* __restrict__ outf) {
  const int K = 256;
  int b = blockIdx.z;
  int m0 = blockIdx.x * 128, n0 = blockIdx.y * 128;
  const short* Ap = (MODE == 0) ? A + (size_t)b * NPOS * K : A;
  const short* Bp = (MODE == 0) ? Bm : Bm + (size_t)b * NPOS * K;

  __shared__ short As[128 * 64], Bs[128 * 64];
  int t = threadIdx.x;
  int lane = t & 63, wid = t >> 6;
  int wm = wid >> 1, wn = wid & 1;
  f32x4 acc[4][4] = {};

  for (int kt = 0; kt < 4; ++kt) {
    int k0 = kt * 64;
    short8 av[4], bv[4];
    #pragma unroll
    for (int p = 0; p < 4; ++p) {
      int ci = t + p * 256;
      int row = ci >> 3, ch = ci & 7;
      av[p] = *(const short8*)(Ap + (size_t)(m0 + row) * K + k0 + ch * 8);
      bv[p] = *(const short8*)(Bp + (size_t)(n0 + row) * K + k0 + ch * 8);
    }
    __syncthreads();
    #pragma unroll
    for (int p = 0; p < 4; ++p) {
      int ci = t + p * 256;
      int row = ci >> 3, ch = ci & 7;
      int off = (row * 128 + ch * 16) ^ ((row & 7) << 4);
      *(short8*)((char*)As + off) = av[p];
      *(short8*)((char*)Bs + off) = bv[p];
    }
    __syncthreads();
    #pragma unroll
    for (int ks = 0; ks < 2; ++ks) {
      short8 af[4], bf[4];
      int inner = ks * 64 + (lane >> 4) * 16;
      #pragma unroll
      for (int mi = 0; mi < 4; ++mi) {
        int row = wm * 64 + mi * 16 + (lane & 15);
        af[mi] = *(short8*)((char*)As + ((row * 128 + inner) ^ ((row & 7) << 4)));
      }
      #pragma unroll
      for (int ni = 0; ni < 4; ++ni) {
        int row = wn * 64 + ni * 16 + (lane & 15);
        bf[ni] = *(short8*)((char*)Bs + ((row * 128 + inner) ^ ((row & 7) << 4)));
      }
      #pragma unroll
      for (int mi = 0; mi < 4; ++mi)
        #pragma unroll
        for (int ni = 0; ni < 4; ++ni)
          acc[mi][ni] = __builtin_amdgcn_mfma_f32_16x16x32_bf16(af[mi], bf[ni], acc[mi][ni], 0, 0, 0);
    }
  }

  #pragma unroll
  for (int mi = 0; mi < 4; ++mi)
    #pragma unroll
    for (int ni = 0; ni < 4; ++ni) {
      int gcol = n0 + wn * 64 + ni * 16 + (lane & 15);
      #pragma unroll
      for (int r = 0; r < 4; ++r) {
        int grow = m0 + wm * 64 + mi * 16 + (lane >> 4) * 4 + r;
        if (MODE == 0) {
          float v = acc[mi][ni][r] + bias[gcol];
          short h = f2b(v);
          if (gcol < 256)       qb[((size_t)b * NPOS + grow) * DIM + gcol] = h;
          else if (gcol < 512)  kb[((size_t)b * NPOS + grow) * DIM + gcol - 256] = h;
          else                  vtb[((size_t)b * DIM + gcol - 512) * NPOS + grow] = h;
        } else {
          float v = acc[mi][ni][r] + bias[grow];
          size_t idx = ((size_t)b * DIM + grow) * NPOS + gcol;
          outf[idx] = v + resid[idx];
        }
      }
    }
}

// ---- flash attention v3b: 4 waves = 2 q-subtiles(16) x 2 kv-halves(2048), KVBLK=32 ----
// Swapped QK^T (mfma(K,Q) -> S^T): softmax in-lane; P via cvt_pk -> short4v stores.
// LDS (79360 B): K0@0 K1@16896 (32x528B rows), V0@33792 V1@54272 (256x80B rows),
//                P@74752 (4x1024), lm@78848. Scratch (combine) aliases K region.
__launch_bounds__(256, 2)
__global__ void k_flash(const short* __restrict__ qb, const short* __restrict__ kb,
                        const short* __restrict__ vtb, short* __restrict__ ob) {
  __shared__ __align__(16) char smem[79360];

  // XCD-aware decode: xcd = i&7 -> batch b = xcd>>1 (one batch's KV per L2 pair)
  int i = blockIdx.x;
  int xcd = i & 7, slot = i >> 3;
  int b = xcd >> 1;
  int bx = slot * 2 + (xcd & 1);   // 0..127
  int q0 = bx * 32;

  int t = threadIdx.x, lane = t & 63, g = lane >> 4, wid = t >> 6;
  int qs = wid & 1, h = wid >> 1;

  const short* kbB = kb + (size_t)b * NPOS * DIM;
  const short* vbB = vtb + (size_t)b * DIM * NPOS;

  // ---- Q fragments (B-operand of swapped QK^T), pre-scaled by 1/16 (exact) ----
  short8 qf[8];
  {
    int qrow = q0 + qs * 16 + (lane & 15);
    const short* qp = qb + ((size_t)b * NPOS + qrow) * DIM + g * 8;
    #pragma unroll
    for (int s = 0; s < 8; ++s) {
      short8 v = *(const short8*)(qp + s * 32);
      #pragma unroll
      for (int j = 0; j < 8; ++j) {
        float f = __uint_as_float(((unsigned)(unsigned short)v[j]) << 16) * 0.0625f;
        v[j] = f2b(f);
      }
      qf[s] = v;
    }
  }

  // staging global bases (per thread)
  const short* A0 = kbB + (t >> 5) * 256 + (t & 31) * 8;   // K: +h*524288 +pp*2048 +it*8192
  const short* B0 = vbB + (t >> 2) * 4096 + (t & 3) * 8;   // V: +pp*262144 +h*2048 +it*32

  // LDS read bases (per lane)
  int krd = h * 16896 + (lane & 15) * 528 + g * 16;        // + t2*8448 + s*64
  int vrd = 33792 + h * 20480 + (lane & 15) * 80 + g * 16; // + nt*1280
  char* prow = smem + 74752 + wid * 1024 + (lane & 15) * 64;
  float* lm = (float*)(smem + 78848);
  float* scratch = (float*)smem;

  // staging LDS write bases (per thread)
  int kwr = (t >> 5) * 528 + (t & 31) * 16;                 // + seg*16896 + pp*4224
  int vwr = 33792 + (t >> 2) * 80 + (t & 3) * 16;           // + seg*20480 + pp*5120

  f32x4 oacc[16] = {};
  float m = -1e30f, l = 0.f;

  short8 st[16];
  #pragma unroll
  for (int p = 0; p < 16; ++p) {
    int seg = p >> 2, pp = p & 3;
    if (seg < 2) st[p] = *(const short8*)(A0 + seg * 524288 + pp * 2048);
    else         st[p] = *(const short8*)(B0 + pp * 262144 + (seg - 2) * 2048);
  }

  const int NIT = 64;
  for (int it = 0; it < NIT; ++it) {
    __syncthreads();   // prev-iter LDS reads complete
    #pragma unroll
    for (int p = 0; p < 16; ++p) {
      int seg = p >> 2, pp = p & 3;
      if (seg < 2) *(short8*)(smem + seg * 16896 + pp * 4224 + kwr) = st[p];
      else         *(short8*)(smem + (seg - 2) * 20480 + pp * 5120 + vwr) = st[p];
    }
    __syncthreads();
    // prefetch next tile into regs (latency hides under compute)
    if (it + 1 < NIT) {
      #pragma unroll
      for (int p = 0; p < 16; ++p) {
        int seg = p >> 2, pp = p & 3;
        if (seg < 2) st[p] = *(const short8*)(A0 + seg * 524288 + pp * 2048 + (it + 1) * 8192);
        else         st[p] = *(const short8*)(B0 + pp * 262144 + (seg - 2) * 2048 + (it + 1) * 32);
      }
    }

    // ---- QK^T (swapped): S^T[32kv x 16q], scale folded into Q ----
    f32x4 sacc[2] = {};
    #pragma unroll
    for (int s = 0; s < 8; ++s) {
      #pragma unroll
      for (int t2 = 0; t2 < 2; ++t2) {
        short8 kf = *(short8*)(smem + krd + t2 * 8448 + s * 64);
        sacc[t2] = __builtin_amdgcn_mfma_f32_16x16x32_bf16(kf, qf[s], sacc[t2], 0, 0, 0);
      }
    }

    // ---- online softmax, in-lane (q = lane&15), defer-max THR=8 ----
    float mx = fmaxf(fmaxf(fmaxf(sacc[0][0], sacc[0][1]), fmaxf(sacc[0][2], sacc[0][3])),
                     fmaxf(fmaxf(sacc[1][0], sacc[1][1]), fmaxf(sacc[1][2], sacc[1][3])));
    mx = fmaxf(mx, __shfl_xor(mx, 16, 64));
    mx = fmaxf(mx, __shfl_xor(mx, 32, 64));
    if (!__all(mx <= m + 8.f)) {
      float mn = fmaxf(m, mx);
      float al = __expf(m - mn);
      m = mn; l *= al;
      #pragma unroll
      for (int r = 0; r < 4; ++r) {
        float ar = __shfl(al, (lane & 48) + ((lane & 48) >> 2) + r, 64);
        #pragma unroll
        for (int nt = 0; nt < 16; ++nt) oacc[nt][r] *= ar;
      }
    }
    float p0 = __expf(sacc[0][0] - m), p1 = __expf(sacc[0][1] - m);
    float p2 = __expf(sacc[0][2] - m), p3 = __expf(sacc[0][3] - m);
    float p4 = __expf(sacc[1][0] - m), p5 = __expf(sacc[1][1] - m);
    float p6 = __expf(sacc[1][2] - m), p7 = __expf(sacc[1][3] - m);
    float ts = ((p0 + p1) + (p2 + p3)) + ((p4 + p5) + (p6 + p7));
    ts += __shfl_xor(ts, 16, 64);
    ts += __shfl_xor(ts, 32, 64);
    l += ts;

    // ---- P -> bf16, wave-private LDS (same elem type as load: short) ----
    unsigned w0, w1, w2, w3;
    asm("v_cvt_pk_bf16_f32 %0, %1, %2" : "=v"(w0) : "v"(p0), "v"(p1));
    asm("v_cvt_pk_bf16_f32 %0, %1, %2" : "=v"(w1) : "v"(p2), "v"(p3));
    asm("v_cvt_pk_bf16_f32 %0, %1, %2" : "=v"(w2) : "v"(p4), "v"(p5));
    asm("v_cvt_pk_bf16_f32 %0, %1, %2" : "=v"(w3) : "v"(p6), "v"(p7));
    *(short4v*)(prow + g * 8)      = __builtin_bit_cast(short4v, (u32x2){w0, w1});
    *(short4v*)(prow + 32 + g * 8) = __builtin_bit_cast(short4v, (u32x2){w2, w3});
    asm volatile("" ::: "memory");   // pin P stores before the pa load

    // ---- PV: O[16q x 256d] += P[16q x 32kv] * V[32kv x 256d] ----
    short8 pa = *(short8*)(prow + g * 16);
    #pragma unroll
    for (int nt = 0; nt < 16; ++nt) {
      short8 vf = *(short8*)(smem + vrd + nt * 1280);
      oacc[nt] = __builtin_amdgcn_mfma_f32_16x16x32_bf16(pa, vf, oacc[nt], 0, 0, 0);
    }
  }

  // ---- combine the two kv-halves (per q-subtile) ----
  __syncthreads();
  if (lane < 16) { lm[wid * 32 + lane * 2] = m; lm[wid * 32 + lane * 2 + 1] = l; }
  __syncthreads();
  int pw = wid ^ 2;
  float mo = lm[pw * 32 + (lane & 15) * 2];
  float lo = lm[pw * 32 + (lane & 15) * 2 + 1];
  float M = fmaxf(m, mo);
  float al = __expf(m - M);
  float Lf = l * al + lo * __expf(mo - M);
  float alr[4], iLr[4];
  #pragma unroll
  for (int r = 0; r < 4; ++r) {
    int src = (lane & 48) + ((lane & 48) >> 2) + r;
    alr[r] = __shfl(al, src, 64);
    iLr[r] = 1.f / __shfl(Lf, src, 64);
  }
  __syncthreads();  // K region now dead -> scratch
  if (h == 0) {
    float* sc = scratch + qs * 4096;
    #pragma unroll
    for (int nt = 0; nt < 16; ++nt)
      #pragma unroll
      for (int r = 0; r < 4; ++r) {
        int q = 4 * g + r;
        int col = nt * 16 + (lane & 15);
        sc[(q * 256 + col) ^ ((g & 1) << 4)] = oacc[nt][r] * alr[r];
      }
  }
  __syncthreads();
  if (h == 1) {
    float* sc = scratch + qs * 4096;
    #pragma unroll
    for (int nt = 0; nt < 16; ++nt)
      #pragma unroll
      for (int r = 0; r < 4; ++r) {
        int q = 4 * g + r;
        int col = nt * 16 + (lane & 15);
        float v = (sc[(q * 256 + col) ^ ((g & 1) << 4)] + oacc[nt][r] * alr[r]) * iLr[r];
        ob[((size_t)b * NPOS + q0 + qs * 16 + q) * DIM + col] = f2b(v);
      }
  }
}

extern "C" void kernel_launch(void* const* d_in, const int* in_sizes, int n_in,
                              void* d_out, int out_size, void* d_ws, size_t ws_size,
                              hipStream_t stream) {
  const float* x     = (const float*)d_in[0];
  const float* gamma = (const float*)d_in[1];
  const float* beta  = (const float*)d_in[2];
  const float* wqkv  = (const float*)d_in[3];
  const float* bqkv  = (const float*)d_in[4];
  const float* wproj = (const float*)d_in[5];
  const float* bproj = (const float*)d_in[6];
  float* out = (float*)d_out;

  char* ws = (char*)d_ws;
  float* stats = (float*)ws;
  short* wqb = (short*)(ws + 1024);
  short* wpb = (short*)(ws + 1024 + 393216);
  size_t off = 1024 + 393216 + 131072;
  const size_t SZ = (size_t)NB * NPOS * DIM * sizeof(short);  // 8 MB
  short* ht   = (short*)(ws + off); off += SZ;
  short* qbuf = (short*)(ws + off); off += SZ;
  short* kbuf = (short*)(ws + off); off += SZ;
  short* vtb  = (short*)(ws + off); off += SZ;
  short* obuf = ht;  // h_t dead after QKV gemm; reuse for attention output

  k_convert_w<<<768, 256, 0, stream>>>(wqkv, wproj, wqb, wpb);
  k_gn_stats<<<128, 256, 0, stream>>>(x, stats);
  k_gn_apply<<<dim3(4, 64, NB), 256, 0, stream>>>(x, stats, gamma, beta, ht);
  k_gemm<0><<<dim3(32, 6, NB), 256, 0, stream>>>(ht, wqb, bqkv, qbuf, kbuf, vtb, nullptr, nullptr);
  k_flash<<<dim3(512), 256, 0, stream>>>(qbuf, kbuf, vtb, obuf);
  k_gemm<1><<<dim3(2, 32, NB), 256, 0, stream>>>(wpb, obuf, bproj, nullptr, nullptr, nullptr, x, out);
}